// Round 6
// baseline (200.608 us; speedup 1.0000x reference)
//
#include <hip/hip_runtime.h>

typedef unsigned short u16;
typedef __attribute__((ext_vector_type(8))) short short8;
typedef __attribute__((ext_vector_type(4))) float floatx4;

#define P_PAIRS 15872
#define E_DIM   768
#define D2      1536
#define OUT_ENT   (512*1536)
#define OUT_REL   (15872*512)

__device__ __forceinline__ u16 f2bf(float f){
    union { float f; unsigned u; } v; v.f = f;
    unsigned r = v.u + 0x7fffu + ((v.u >> 16) & 1u);   // RNE
    return (u16)(r >> 16);
}
__device__ __forceinline__ unsigned pack2(float a, float b){
    return (unsigned)f2bf(a) | ((unsigned)f2bf(b) << 16);
}
// async global->LDS, 16B per lane; lds base wave-uniform (lane*16 auto-added)
__device__ __forceinline__ void async_ld16(const void* g, void* lds_base){
    __builtin_amdgcn_global_load_lds(
        (const __attribute__((address_space(1))) unsigned*)g,
        (__attribute__((address_space(3))) unsigned*)lds_base, 16, 0, 0);
}

// ================= prep: W1T, Ws1T, W2T transposes (+bf16) and entity gather =================
__global__ __launch_bounds__(256)
void prep_k(const float* __restrict__ W1, const float* __restrict__ Ws1,
            const float* __restrict__ W2, const float* __restrict__ x,
            const int* __restrict__ ann,
            u16* __restrict__ W1T, u16* __restrict__ Ws1T, u16* __restrict__ W2T,
            float* __restrict__ entF, u16* __restrict__ entB) {
    const int bid = blockIdx.x;
    const int t = threadIdx.x;
    if (bid < 3328) {
        __shared__ float tile[32][33];
        const float* src; u16* dst; int R, C, b;
        if (bid < 1536)      { src = W1;  dst = W1T;  R = 3072; C = 512; b = bid; }
        else if (bid < 3072) { src = Ws1; dst = Ws1T; R = 3072; C = 512; b = bid - 1536; }
        else                 { src = W2;  dst = W2T;  R = 512;  C = 512; b = bid - 3072; }
        const int bx = (b & 15) * 32;
        const int by = (b >> 4) * 32;
        const int tx = t & 31, ty = t >> 5;
#pragma unroll
        for (int i = 0; i < 32; i += 8)
            tile[ty + i][tx] = src[(size_t)(by + ty + i) * C + bx + tx];
        __syncthreads();
#pragma unroll
        for (int i = 0; i < 32; i += 8)
            dst[(size_t)(bx + ty + i) * R + by + tx] = f2bf(tile[tx][ty + i]);
    } else {
        const int e = bid - 3328;            // 0..511
#pragma unroll
        for (int pass = 0; pass < 2; pass++) {
            const int c = t + pass * 256;    // float4 chunk 0..383
            if (c >= 384) break;
            const int half = c / 192;
            const int tok = ann[e * 2 + half];
            const int b = e >> 5;
            const float4 v = ((const float4*)(x + (size_t)(b * 512 + tok) * E_DIM))[c % 192];
            ((float4*)(entF + (size_t)e * D2))[c] = v;
            uint2 o; o.x = pack2(v.x, v.y); o.y = pack2(v.z, v.w);
            ((uint2*)(entB + (size_t)e * D2))[c] = o;
        }
    }
}

// ================= gemm_uv: UV[4][512][512] = EntB @ {W1T|Ws1T} =================
// 64x64 tiles, BK=64, double-buffered LDS, XOR-swizzled.
// biases folded: g==0 adds b1[col] (U), g==2 adds bs1[col] (Us).
__global__ __launch_bounds__(256)
void gemm_uv(const u16* __restrict__ Ent, const u16* __restrict__ W1T,
             const u16* __restrict__ Ws1T, const float* __restrict__ b1,
             const float* __restrict__ bs1, float* __restrict__ UV) {
    __shared__ __align__(16) u16 As[2][64 * 64];
    __shared__ __align__(16) u16 Bs[2][64 * 64];
    const int t = threadIdx.x;
    const int bid = blockIdx.x;
    const int m0 = (bid & 7) * 64;
    const int n0g = (bid >> 3) * 64;
    const int g = n0g >> 9;
    const int n0 = n0g & 511;
    const u16* WT = (g < 2) ? W1T : Ws1T;
    const int koff = (g & 1) * D2;

    const int wave = t >> 6, lane = t & 63;
    const int wm = (wave >> 1) * 32, wn = (wave & 1) * 32;
    const int l15 = lane & 15, quad = lane >> 4;

    const int lr = lane >> 3;
    const int k8 = (lane & 7) ^ lr;
    const int rowA0 = wave * 16 + lr;
    const u16* gA0 = Ent + (size_t)(m0 + rowA0) * D2 + k8 * 8;
    const u16* gA1 = Ent + (size_t)(m0 + rowA0 + 8) * D2 + k8 * 8;
    const u16* gB0 = WT + (size_t)(n0 + rowA0) * 3072 + koff + k8 * 8;
    const u16* gB1 = WT + (size_t)(n0 + rowA0 + 8) * 3072 + koff + k8 * 8;
    const int lofs0 = wave * 1024, lofs1 = wave * 1024 + 512;

    floatx4 acc[2][2] = {};
    async_ld16(gA0, As[0] + lofs0);
    async_ld16(gA1, As[0] + lofs1);
    async_ld16(gB0, Bs[0] + lofs0);
    async_ld16(gB1, Bs[0] + lofs1);
    for (int i = 0; i < 24; i++) {
        const int cur = i & 1;
        __syncthreads();
        if (i + 1 < 24) {
            const int k1 = (i + 1) * 64;
            async_ld16(gA0 + k1, As[cur ^ 1] + lofs0);
            async_ld16(gA1 + k1, As[cur ^ 1] + lofs1);
            async_ld16(gB0 + k1, Bs[cur ^ 1] + lofs0);
            async_ld16(gB1 + k1, Bs[cur ^ 1] + lofs1);
        }
        const u16* Ac = As[cur];
        const u16* Bc = Bs[cur];
#pragma unroll
        for (int kk = 0; kk < 2; kk++) {
            short8 af[2], bf[2];
#pragma unroll
            for (int i2 = 0; i2 < 2; i2++) {
                const int ra = wm + i2 * 16 + l15;
                af[i2] = *(const short8*)(Ac + (ra * 8 + ((quad + kk * 4) ^ (ra & 7))) * 8);
                const int rb = wn + i2 * 16 + l15;
                bf[i2] = *(const short8*)(Bc + (rb * 8 + ((quad + kk * 4) ^ (rb & 7))) * 8);
            }
#pragma unroll
            for (int i2 = 0; i2 < 2; i2++)
#pragma unroll
                for (int j2 = 0; j2 < 2; j2++)
                    acc[i2][j2] = __builtin_amdgcn_mfma_f32_16x16x32_bf16(af[i2], bf[j2], acc[i2][j2], 0, 0, 0);
        }
    }
    float* outg = UV + (size_t)g * 262144;
#pragma unroll
    for (int j = 0; j < 2; j++) {
        const int col = n0 + wn + j * 16 + l15;
        const float bias = (g == 0) ? b1[col] : (g == 2) ? bs1[col] : 0.f;
#pragma unroll
        for (int i = 0; i < 2; i++) {
            const int rowb = m0 + wm + i * 16 + quad * 4;
#pragma unroll
            for (int r = 0; r < 4; r++)
                outg[(size_t)(rowb + r) * 512 + col] = acc[i][j][r] + bias;
        }
    }
}

// ================= rel_score: [0,496) GEMM, A built in-register; [496,992) scores =================
__global__ __launch_bounds__(256)
void rel_score_k(const float* __restrict__ UV, const int* __restrict__ left,
                 const int* __restrict__ right, const float* __restrict__ Ws2,
                 const float* __restrict__ bs2, const u16* __restrict__ W2T,
                 const float* __restrict__ b2, float* __restrict__ rel,
                 float* __restrict__ score) {
    const int bid = blockIdx.x;
    const int t = threadIdx.x;
    const int wave = t >> 6, lane = t & 63;

    if (bid < 496) {
        // rel[m0+128, n0+128] = relu(U'[l] + V[r]) @ W2 + b2   (U' has b1 folded)
        __shared__ __align__(16) u16 Bs[2][128 * 32];
        const int m0 = (bid >> 2) * 128;
        const int n0 = (bid & 3) * 128;
        const int wm = (wave >> 1) * 64, wn = (wave & 1) * 64;
        const int l15 = lane & 15, quad = lane >> 4;

        // per-lane A rows for the 4 m-fragments; A built in registers from UV
        const float* Au[4];
        const float* Av[4];
#pragma unroll
        for (int i2 = 0; i2 < 4; i2++) {
            const int row = m0 + wm + i2 * 16 + l15;
            Au[i2] = UV + (size_t)left[row] * 512 + quad * 8;
            Av[i2] = UV + 262144 + (size_t)right[row] * 512 + quad * 8;
        }
        // B staging: XOR-4 swizzle, async dbuf
        const int browl = lane >> 2;
        const int bk8 = (lane & 3) ^ (browl & 3);
        const u16* gB0 = W2T + (size_t)(n0 + wave * 32 + browl) * 512 + bk8 * 8;
        const u16* gB1 = W2T + (size_t)(n0 + wave * 32 + 16 + browl) * 512 + bk8 * 8;
        const int lofs0 = wave * 1024, lofs1 = wave * 1024 + 512;

        floatx4 acc[4][4] = {};
        float4 pu[4][2], pv[4][2];
#pragma unroll
        for (int i2 = 0; i2 < 4; i2++) {
            pu[i2][0] = *(const float4*)(Au[i2]);
            pu[i2][1] = *(const float4*)(Au[i2] + 4);
            pv[i2][0] = *(const float4*)(Av[i2]);
            pv[i2][1] = *(const float4*)(Av[i2] + 4);
        }
        async_ld16(gB0, Bs[0] + lofs0);
        async_ld16(gB1, Bs[0] + lofs1);

        for (int i = 0; i < 16; i++) {
            const int cur = i & 1;
            __syncthreads();                   // B[cur] ready; B[cur^1] free
            if (i + 1 < 16) {
                const int k1 = (i + 1) * 32;
                async_ld16(gB0 + k1, Bs[cur ^ 1] + lofs0);
                async_ld16(gB1 + k1, Bs[cur ^ 1] + lofs1);
            }
            // build A fragments in-register from prefetched U/V
            short8 af[4];
#pragma unroll
            for (int i2 = 0; i2 < 4; i2++) {
                const float4 a0 = pu[i2][0], a1 = pu[i2][1];
                const float4 c0 = pv[i2][0], c1 = pv[i2][1];
                union { unsigned u[4]; short8 s; } w;
                w.u[0] = pack2(fmaxf(a0.x + c0.x, 0.f), fmaxf(a0.y + c0.y, 0.f));
                w.u[1] = pack2(fmaxf(a0.z + c0.z, 0.f), fmaxf(a0.w + c0.w, 0.f));
                w.u[2] = pack2(fmaxf(a1.x + c1.x, 0.f), fmaxf(a1.y + c1.y, 0.f));
                w.u[3] = pack2(fmaxf(a1.z + c1.z, 0.f), fmaxf(a1.w + c1.w, 0.f));
                af[i2] = w.s;
            }
            // prefetch next iter's U/V (L2-resident)
            if (i + 1 < 16) {
                const int k1 = (i + 1) * 32;
#pragma unroll
                for (int i2 = 0; i2 < 4; i2++) {
                    pu[i2][0] = *(const float4*)(Au[i2] + k1);
                    pu[i2][1] = *(const float4*)(Au[i2] + k1 + 4);
                    pv[i2][0] = *(const float4*)(Av[i2] + k1);
                    pv[i2][1] = *(const float4*)(Av[i2] + k1 + 4);
                }
            }
            const u16* Bc = Bs[cur];
            short8 bf[4];
#pragma unroll
            for (int j2 = 0; j2 < 4; j2++) {
                const int rb = wn + j2 * 16 + l15;
                bf[j2] = *(const short8*)(Bc + (rb * 4 + (quad ^ (rb & 3))) * 8);
            }
#pragma unroll
            for (int i2 = 0; i2 < 4; i2++)
#pragma unroll
                for (int j2 = 0; j2 < 4; j2++)
                    acc[i2][j2] = __builtin_amdgcn_mfma_f32_16x16x32_bf16(af[i2], bf[j2], acc[i2][j2], 0, 0, 0);
        }
#pragma unroll
        for (int j = 0; j < 4; j++) {
            const int col = n0 + wn + j * 16 + l15;
            const float bias = b2[col];
#pragma unroll
            for (int i = 0; i < 4; i++) {
                const int rowb = m0 + wm + i * 16 + quad * 4;
#pragma unroll
                for (int r = 0; r < 4; r++)
                    rel[(size_t)(rowb + r) * 512 + col] = acc[i][j][r] + bias;
            }
        }
    } else {
        // scores: 32 pairs/block, 8/wave.  Us' has bs1 folded.
        const int pid0 = (bid - 496) * 32 + wave * 8;
        const float4* Wsp = (const float4*)(Ws2 + lane * 8);
        const float4 w0 = Wsp[0], w1 = Wsp[1];
        const float bias = bs2[0];
#pragma unroll
        for (int it = 0; it < 8; it++) {
            const int p = pid0 + it;
            const int l = left[p], r = right[p];
            const float4* us = (const float4*)(UV + 2 * 262144 + (size_t)l * 512 + lane * 8);
            const float4* vs = (const float4*)(UV + 3 * 262144 + (size_t)r * 512 + lane * 8);
            const float4 a0 = us[0], a1 = us[1];
            const float4 c0 = vs[0], c1 = vs[1];
            float acc;
            acc  = fmaxf(a0.x + c0.x, 0.f) * w0.x;
            acc += fmaxf(a0.y + c0.y, 0.f) * w0.y;
            acc += fmaxf(a0.z + c0.z, 0.f) * w0.z;
            acc += fmaxf(a0.w + c0.w, 0.f) * w0.w;
            acc += fmaxf(a1.x + c1.x, 0.f) * w1.x;
            acc += fmaxf(a1.y + c1.y, 0.f) * w1.y;
            acc += fmaxf(a1.z + c1.z, 0.f) * w1.z;
            acc += fmaxf(a1.w + c1.w, 0.f) * w1.w;
#pragma unroll
            for (int off = 32; off; off >>= 1) acc += __shfl_down(acc, off, 64);
            if (lane == 0) score[p] = fabsf(acc + bias);
        }
    }
}

extern "C" void kernel_launch(void* const* d_in, const int* in_sizes, int n_in,
                              void* d_out, int out_size, void* d_ws, size_t ws_size,
                              hipStream_t stream) {
    const float* x   = (const float*)d_in[0];
    const int* ann   = (const int*)d_in[3];
    const int* left  = (const int*)d_in[5];
    const int* right = (const int*)d_in[6];
    const float* W1  = (const float*)d_in[7];
    const float* b1  = (const float*)d_in[8];
    const float* W2  = (const float*)d_in[9];
    const float* b2  = (const float*)d_in[10];
    const float* Ws1 = (const float*)d_in[11];
    const float* bs1 = (const float*)d_in[12];
    const float* Ws2 = (const float*)d_in[13];
    const float* bs2 = (const float*)d_in[14];

    float* out = (float*)d_out;
    float* entF = out;                       // output 0 (exact fp32 copy)
    float* rel  = out + OUT_ENT;             // output 1
    float* sco  = out + OUT_ENT + OUT_REL;   // output 2

    u16* W1T  = (u16*)d_ws;                  // 512*3072 bf16 (B^T)
    u16* Ws1T = W1T + 512 * 3072;
    u16* W2T  = Ws1T + 512 * 3072;           // 512*512 bf16
    u16* EntB = W2T + 512 * 512;             // 512*1536 bf16
    float* UV = (float*)(EntB + 512 * 1536); // [4][512][512] fp32: U+b1, V, Us+bs1, Vs

    prep_k<<<3840, 256, 0, stream>>>(W1, Ws1, W2, x, ann, W1T, Ws1T, W2T, entF, EntB);
    gemm_uv<<<256, 256, 0, stream>>>(EntB, W1T, Ws1T, b1, bs1, UV);
    rel_score_k<<<992, 256, 0, stream>>>(UV, left, right, Ws2, bs2, W2T, b2, rel, sco);
}

// Round 7
// 158.731 us; speedup vs baseline: 1.2638x; 1.2638x over previous
//
#include <hip/hip_runtime.h>

typedef unsigned short u16;
typedef __attribute__((ext_vector_type(8))) short short8;
typedef __attribute__((ext_vector_type(4))) float floatx4;

#define P_PAIRS 15872
#define E_DIM   768
#define D2      1536
#define OUT_ENT   (512*1536)
#define OUT_REL   (15872*512)

__device__ __forceinline__ u16 f2bf(float f){
    union { float f; unsigned u; } v; v.f = f;
    unsigned r = v.u + 0x7fffu + ((v.u >> 16) & 1u);   // RNE
    return (u16)(r >> 16);
}
__device__ __forceinline__ unsigned pack2(float a, float b){
    return (unsigned)f2bf(a) | ((unsigned)f2bf(b) << 16);
}
// async global->LDS, 16B per lane; lds base wave-uniform (lane*16 auto-added)
__device__ __forceinline__ void async_ld16(const void* g, void* lds_base){
    __builtin_amdgcn_global_load_lds(
        (const __attribute__((address_space(1))) unsigned*)g,
        (__attribute__((address_space(3))) unsigned*)lds_base, 16, 0, 0);
}

// ================= prep: W1T, Ws1T, W2T transposes (+bf16) and entity gather =================
__global__ __launch_bounds__(256)
void prep_k(const float* __restrict__ W1, const float* __restrict__ Ws1,
            const float* __restrict__ W2, const float* __restrict__ x,
            const int* __restrict__ ann,
            u16* __restrict__ W1T, u16* __restrict__ Ws1T, u16* __restrict__ W2T,
            float* __restrict__ entF, u16* __restrict__ entB) {
    const int bid = blockIdx.x;
    const int t = threadIdx.x;
    if (bid < 3328) {
        __shared__ float tile[32][33];
        const float* src; u16* dst; int R, C, b;
        if (bid < 1536)      { src = W1;  dst = W1T;  R = 3072; C = 512; b = bid; }
        else if (bid < 3072) { src = Ws1; dst = Ws1T; R = 3072; C = 512; b = bid - 1536; }
        else                 { src = W2;  dst = W2T;  R = 512;  C = 512; b = bid - 3072; }
        const int bx = (b & 15) * 32;
        const int by = (b >> 4) * 32;
        const int tx = t & 31, ty = t >> 5;
#pragma unroll
        for (int i = 0; i < 32; i += 8)
            tile[ty + i][tx] = src[(size_t)(by + ty + i) * C + bx + tx];
        __syncthreads();
#pragma unroll
        for (int i = 0; i < 32; i += 8)
            dst[(size_t)(bx + ty + i) * R + by + tx] = f2bf(tile[tx][ty + i]);
    } else {
        const int e = bid - 3328;            // 0..511
#pragma unroll
        for (int pass = 0; pass < 2; pass++) {
            const int c = t + pass * 256;    // float4 chunk 0..383
            if (c >= 384) break;
            const int half = c / 192;
            const int tok = ann[e * 2 + half];
            const int b = e >> 5;
            const float4 v = ((const float4*)(x + (size_t)(b * 512 + tok) * E_DIM))[c % 192];
            ((float4*)(entF + (size_t)e * D2))[c] = v;
            uint2 o; o.x = pack2(v.x, v.y); o.y = pack2(v.z, v.w);
            ((uint2*)(entB + (size_t)e * D2))[c] = o;
        }
    }
}

// ================= gemm_uv: UV[4][512][512] = EntB @ {W1T|Ws1T} =================
// 64x64 tiles, BK=64, double-buffered LDS, XOR-swizzled.
// biases folded: g==0 adds b1[col] (U), g==2 adds bs1[col] (Us).
__global__ __launch_bounds__(256)
void gemm_uv(const u16* __restrict__ Ent, const u16* __restrict__ W1T,
             const u16* __restrict__ Ws1T, const float* __restrict__ b1,
             const float* __restrict__ bs1, float* __restrict__ UV) {
    __shared__ __align__(16) u16 As[2][64 * 64];
    __shared__ __align__(16) u16 Bs[2][64 * 64];
    const int t = threadIdx.x;
    const int bid = blockIdx.x;
    const int m0 = (bid & 7) * 64;
    const int n0g = (bid >> 3) * 64;
    const int g = n0g >> 9;
    const int n0 = n0g & 511;
    const u16* WT = (g < 2) ? W1T : Ws1T;
    const int koff = (g & 1) * D2;

    const int wave = t >> 6, lane = t & 63;
    const int wm = (wave >> 1) * 32, wn = (wave & 1) * 32;
    const int l15 = lane & 15, quad = lane >> 4;

    const int lr = lane >> 3;
    const int k8 = (lane & 7) ^ lr;
    const int rowA0 = wave * 16 + lr;
    const u16* gA0 = Ent + (size_t)(m0 + rowA0) * D2 + k8 * 8;
    const u16* gA1 = Ent + (size_t)(m0 + rowA0 + 8) * D2 + k8 * 8;
    const u16* gB0 = WT + (size_t)(n0 + rowA0) * 3072 + koff + k8 * 8;
    const u16* gB1 = WT + (size_t)(n0 + rowA0 + 8) * 3072 + koff + k8 * 8;
    const int lofs0 = wave * 1024, lofs1 = wave * 1024 + 512;

    floatx4 acc[2][2] = {};
    async_ld16(gA0, As[0] + lofs0);
    async_ld16(gA1, As[0] + lofs1);
    async_ld16(gB0, Bs[0] + lofs0);
    async_ld16(gB1, Bs[0] + lofs1);
    for (int i = 0; i < 24; i++) {
        const int cur = i & 1;
        __syncthreads();
        if (i + 1 < 24) {
            const int k1 = (i + 1) * 64;
            async_ld16(gA0 + k1, As[cur ^ 1] + lofs0);
            async_ld16(gA1 + k1, As[cur ^ 1] + lofs1);
            async_ld16(gB0 + k1, Bs[cur ^ 1] + lofs0);
            async_ld16(gB1 + k1, Bs[cur ^ 1] + lofs1);
        }
        const u16* Ac = As[cur];
        const u16* Bc = Bs[cur];
#pragma unroll
        for (int kk = 0; kk < 2; kk++) {
            short8 af[2], bf[2];
#pragma unroll
            for (int i2 = 0; i2 < 2; i2++) {
                const int ra = wm + i2 * 16 + l15;
                af[i2] = *(const short8*)(Ac + (ra * 8 + ((quad + kk * 4) ^ (ra & 7))) * 8);
                const int rb = wn + i2 * 16 + l15;
                bf[i2] = *(const short8*)(Bc + (rb * 8 + ((quad + kk * 4) ^ (rb & 7))) * 8);
            }
#pragma unroll
            for (int i2 = 0; i2 < 2; i2++)
#pragma unroll
                for (int j2 = 0; j2 < 2; j2++)
                    acc[i2][j2] = __builtin_amdgcn_mfma_f32_16x16x32_bf16(af[i2], bf[j2], acc[i2][j2], 0, 0, 0);
        }
    }
    float* outg = UV + (size_t)g * 262144;
#pragma unroll
    for (int j = 0; j < 2; j++) {
        const int col = n0 + wn + j * 16 + l15;
        const float bias = (g == 0) ? b1[col] : (g == 2) ? bs1[col] : 0.f;
#pragma unroll
        for (int i = 0; i < 2; i++) {
            const int rowb = m0 + wm + i * 16 + quad * 4;
#pragma unroll
            for (int r = 0; r < 4; r++)
                outg[(size_t)(rowb + r) * 512 + col] = acc[i][j][r] + bias;
        }
    }
}

// ================= rel_score: [0,496) fused-H GEMM (LDS-staged A, dbuf); [496,992) scores =================
__global__ __launch_bounds__(256)
void rel_score_k(const float* __restrict__ UV, const int* __restrict__ left,
                 const int* __restrict__ right, const float* __restrict__ Ws2,
                 const float* __restrict__ bs2, const u16* __restrict__ W2T,
                 const float* __restrict__ b2, float* __restrict__ rel,
                 float* __restrict__ score) {
    const int bid = blockIdx.x;
    const int t = threadIdx.x;
    const int wave = t >> 6, lane = t & 63;

    if (bid < 496) {
        // rel[m0+128, n0+128] = relu(U'[l] + V[r]) @ W2 + b2   (U' has b1 folded)
        __shared__ __align__(16) u16 As[2][128 * 32];
        __shared__ __align__(16) u16 Bs[2][128 * 32];
        const int m0 = (bid >> 2) * 128;
        const int n0 = (bid & 3) * 128;
        const int wm = (wave >> 1) * 64, wn = (wave & 1) * 64;
        const int l15 = lane & 15, quad = lane >> 4;

        // A role: thread t -> row arow = t>>1, k-half kh = t&1 (16 elems) — coalesced U/V loads
        const int arow = t >> 1;
        const int kh = t & 1;
        const int li = left[m0 + arow], ri = right[m0 + arow];
        const float4* Up = (const float4*)(UV + (size_t)li * 512 + kh * 16);
        const float4* Vp = (const float4*)(UV + 262144 + (size_t)ri * 512 + kh * 16);
        // A write slots (XOR-4 swizzle): logical k8 in {2kh, 2kh+1}
        const int sA0 = arow * 4 + ((kh * 2) ^ (arow & 3));
        const int sA1 = arow * 4 + ((kh * 2 + 1) ^ (arow & 3));
        // B staging: wave w rows 32w..; row = 32w + (l>>2) (+16), k8 = (l&3)^((l>>2)&3)
        const int browl = lane >> 2;
        const int bk8 = (lane & 3) ^ (browl & 3);
        const u16* gB0 = W2T + (size_t)(n0 + wave * 32 + browl) * 512 + bk8 * 8;
        const u16* gB1 = W2T + (size_t)(n0 + wave * 32 + 16 + browl) * 512 + bk8 * 8;
        const int lofs0 = wave * 1024, lofs1 = wave * 1024 + 512;

        floatx4 acc[4][4] = {};
        float4 uu[4], vv[4];
#pragma unroll
        for (int j = 0; j < 4; j++) { uu[j] = Up[j]; vv[j] = Vp[j]; }
        async_ld16(gB0, Bs[0] + lofs0);
        async_ld16(gB1, Bs[0] + lofs1);
        {
            uint4 h0, h1;
            h0.x = pack2(fmaxf(uu[0].x + vv[0].x, 0.f), fmaxf(uu[0].y + vv[0].y, 0.f));
            h0.y = pack2(fmaxf(uu[0].z + vv[0].z, 0.f), fmaxf(uu[0].w + vv[0].w, 0.f));
            h0.z = pack2(fmaxf(uu[1].x + vv[1].x, 0.f), fmaxf(uu[1].y + vv[1].y, 0.f));
            h0.w = pack2(fmaxf(uu[1].z + vv[1].z, 0.f), fmaxf(uu[1].w + vv[1].w, 0.f));
            h1.x = pack2(fmaxf(uu[2].x + vv[2].x, 0.f), fmaxf(uu[2].y + vv[2].y, 0.f));
            h1.y = pack2(fmaxf(uu[2].z + vv[2].z, 0.f), fmaxf(uu[2].w + vv[2].w, 0.f));
            h1.z = pack2(fmaxf(uu[3].x + vv[3].x, 0.f), fmaxf(uu[3].y + vv[3].y, 0.f));
            h1.w = pack2(fmaxf(uu[3].z + vv[3].z, 0.f), fmaxf(uu[3].w + vv[3].w, 0.f));
            *(uint4*)(As[0] + sA0 * 8) = h0;
            *(uint4*)(As[0] + sA1 * 8) = h1;
        }
#pragma unroll
        for (int j = 0; j < 4; j++) { uu[j] = Up[8 + j]; vv[j] = Vp[8 + j]; }

        for (int i = 0; i < 16; i++) {
            const int cur = i & 1;
            __syncthreads();                   // buf[cur] ready; buf[cur^1] free
            if (i + 1 < 16) {
                const int k1 = (i + 1) * 32;
                async_ld16(gB0 + k1, Bs[cur ^ 1] + lofs0);
                async_ld16(gB1 + k1, Bs[cur ^ 1] + lofs1);
                uint4 h0, h1;
                h0.x = pack2(fmaxf(uu[0].x + vv[0].x, 0.f), fmaxf(uu[0].y + vv[0].y, 0.f));
                h0.y = pack2(fmaxf(uu[0].z + vv[0].z, 0.f), fmaxf(uu[0].w + vv[0].w, 0.f));
                h0.z = pack2(fmaxf(uu[1].x + vv[1].x, 0.f), fmaxf(uu[1].y + vv[1].y, 0.f));
                h0.w = pack2(fmaxf(uu[1].z + vv[1].z, 0.f), fmaxf(uu[1].w + vv[1].w, 0.f));
                h1.x = pack2(fmaxf(uu[2].x + vv[2].x, 0.f), fmaxf(uu[2].y + vv[2].y, 0.f));
                h1.y = pack2(fmaxf(uu[2].z + vv[2].z, 0.f), fmaxf(uu[2].w + vv[2].w, 0.f));
                h1.z = pack2(fmaxf(uu[3].x + vv[3].x, 0.f), fmaxf(uu[3].y + vv[3].y, 0.f));
                h1.w = pack2(fmaxf(uu[3].z + vv[3].z, 0.f), fmaxf(uu[3].w + vv[3].w, 0.f));
                *(uint4*)(As[cur ^ 1] + sA0 * 8) = h0;
                *(uint4*)(As[cur ^ 1] + sA1 * 8) = h1;
                if (i + 2 < 16) {
                    const int q = (i + 2) * 8;
#pragma unroll
                    for (int j = 0; j < 4; j++) { uu[j] = Up[q + j]; vv[j] = Vp[q + j]; }
                }
            }
            const u16* Ac = As[cur];
            const u16* Bc = Bs[cur];
            short8 af[4], bf[4];
#pragma unroll
            for (int i2 = 0; i2 < 4; i2++) {
                const int ra = wm + i2 * 16 + l15;
                af[i2] = *(const short8*)(Ac + (ra * 4 + (quad ^ (ra & 3))) * 8);
                const int rb = wn + i2 * 16 + l15;
                bf[i2] = *(const short8*)(Bc + (rb * 4 + (quad ^ (rb & 3))) * 8);
            }
#pragma unroll
            for (int i2 = 0; i2 < 4; i2++)
#pragma unroll
                for (int j2 = 0; j2 < 4; j2++)
                    acc[i2][j2] = __builtin_amdgcn_mfma_f32_16x16x32_bf16(af[i2], bf[j2], acc[i2][j2], 0, 0, 0);
        }
#pragma unroll
        for (int j = 0; j < 4; j++) {
            const int col = n0 + wn + j * 16 + l15;
            const float bias = b2[col];
#pragma unroll
            for (int i = 0; i < 4; i++) {
                const int rowb = m0 + wm + i * 16 + quad * 4;
#pragma unroll
                for (int r = 0; r < 4; r++)
                    rel[(size_t)(rowb + r) * 512 + col] = acc[i][j][r] + bias;
            }
        }
    } else {
        // scores: 32 pairs/block, 8/wave.  Us' has bs1 folded.
        const int pid0 = (bid - 496) * 32 + wave * 8;
        const float4* Wsp = (const float4*)(Ws2 + lane * 8);
        const float4 w0 = Wsp[0], w1 = Wsp[1];
        const float bias = bs2[0];
#pragma unroll
        for (int it = 0; it < 8; it++) {
            const int p = pid0 + it;
            const int l = left[p], r = right[p];
            const float4* us = (const float4*)(UV + 2 * 262144 + (size_t)l * 512 + lane * 8);
            const float4* vs = (const float4*)(UV + 3 * 262144 + (size_t)r * 512 + lane * 8);
            const float4 a0 = us[0], a1 = us[1];
            const float4 c0 = vs[0], c1 = vs[1];
            float acc;
            acc  = fmaxf(a0.x + c0.x, 0.f) * w0.x;
            acc += fmaxf(a0.y + c0.y, 0.f) * w0.y;
            acc += fmaxf(a0.z + c0.z, 0.f) * w0.z;
            acc += fmaxf(a0.w + c0.w, 0.f) * w0.w;
            acc += fmaxf(a1.x + c1.x, 0.f) * w1.x;
            acc += fmaxf(a1.y + c1.y, 0.f) * w1.y;
            acc += fmaxf(a1.z + c1.z, 0.f) * w1.z;
            acc += fmaxf(a1.w + c1.w, 0.f) * w1.w;
#pragma unroll
            for (int off = 32; off; off >>= 1) acc += __shfl_down(acc, off, 64);
            if (lane == 0) score[p] = fabsf(acc + bias);
        }
    }
}

extern "C" void kernel_launch(void* const* d_in, const int* in_sizes, int n_in,
                              void* d_out, int out_size, void* d_ws, size_t ws_size,
                              hipStream_t stream) {
    const float* x   = (const float*)d_in[0];
    const int* ann   = (const int*)d_in[3];
    const int* left  = (const int*)d_in[5];
    const int* right = (const int*)d_in[6];
    const float* W1  = (const float*)d_in[7];
    const float* b1  = (const float*)d_in[8];
    const float* W2  = (const float*)d_in[9];
    const float* b2  = (const float*)d_in[10];
    const float* Ws1 = (const float*)d_in[11];
    const float* bs1 = (const float*)d_in[12];
    const float* Ws2 = (const float*)d_in[13];
    const float* bs2 = (const float*)d_in[14];

    float* out = (float*)d_out;
    float* entF = out;                       // output 0 (exact fp32 copy)
    float* rel  = out + OUT_ENT;             // output 1
    float* sco  = out + OUT_ENT + OUT_REL;   // output 2

    u16* W1T  = (u16*)d_ws;                  // 512*3072 bf16 (B^T)
    u16* Ws1T = W1T + 512 * 3072;
    u16* W2T  = Ws1T + 512 * 3072;           // 512*512 bf16
    u16* EntB = W2T + 512 * 512;             // 512*1536 bf16
    float* UV = (float*)(EntB + 512 * 1536); // [4][512][512] fp32: U+b1, V, Us+bs1, Vs

    prep_k<<<3840, 256, 0, stream>>>(W1, Ws1, W2, x, ann, W1T, Ws1T, W2T, entF, EntB);
    gemm_uv<<<256, 256, 0, stream>>>(EntB, W1T, Ws1T, b1, bs1, UV);
    rel_score_k<<<992, 256, 0, stream>>>(UV, left, right, Ws2, bs2, W2T, b2, rel, sco);
}